// Round 1
// baseline (363.077 us; speedup 1.0000x reference)
//
#include <hip/hip_runtime.h>
#include <stdint.h>

#define B_ 4
#define L_ 2048
#define D_ 1024
#define H_ 16
#define HD_ 64
#define M_ (B_*L_)   // 8192
#define N3_ (3*D_)   // 3072

typedef _Float16 h8 __attribute__((ext_vector_type(8)));
typedef _Float16 h4v __attribute__((ext_vector_type(4)));
typedef float f4 __attribute__((ext_vector_type(4)));

__device__ __forceinline__ void gload16(const void* g, void* l) {
  __builtin_amdgcn_global_load_lds(
      (const __attribute__((address_space(1))) void*)g,
      (__attribute__((address_space(3))) void*)l, 16, 0, 0);
}

// ---------------- conversion kernels ----------------
__global__ void k_cvt_f16(const float* __restrict__ in, _Float16* __restrict__ out, int n4) {
  int i = blockIdx.x*blockDim.x + threadIdx.x;
  int st = gridDim.x*blockDim.x;
  for (; i < n4; i += st) {
    float4 v = ((const float4*)in)[i];
    h4v o = { (_Float16)v.x, (_Float16)v.y, (_Float16)v.z, (_Float16)v.w };
    ((h4v*)out)[i] = o;
  }
}

// out[c][r] = (f16) in[r][c];  R,C multiples of 32
__global__ void k_transpose_f16(const float* __restrict__ in, _Float16* __restrict__ out, int R, int C) {
  __shared__ float tile[32][33];
  int bc = blockIdx.x*32, br = blockIdx.y*32;
  int tx = threadIdx.x, ty = threadIdx.y;
  #pragma unroll
  for (int j = 0; j < 32; j += 8)
    tile[ty+j][tx] = in[(size_t)(br+ty+j)*C + bc+tx];
  __syncthreads();
  #pragma unroll
  for (int j = 0; j < 32; j += 8)
    out[(size_t)(bc+ty+j)*R + br+tx] = (_Float16)tile[tx][ty+j];
}

// ---------------- GEMM: C(MxN) = A(MxK) * Bt(NxK)^T ----------------
// 128x128 tile, BK=64, 4 waves (2x2), each wave 64x64 via 4x4 16x16x32 frags.
// EPI 0: scatter to Q/K/Vt fp16.  EPI 1: f32 out + bias.
template<int EPI>
__global__ __launch_bounds__(256,2)
void k_gemm(const _Float16* __restrict__ A, const _Float16* __restrict__ Bt,
            float* __restrict__ Cf, const float* __restrict__ bias,
            _Float16* __restrict__ Qo, _Float16* __restrict__ Ko, _Float16* __restrict__ Vo,
            int N, int K, int nbn) {
  __shared__ _Float16 Al[128*64];
  __shared__ _Float16 Bl[128*64];
  int bid = blockIdx.x;
  int bm = bid / nbn, bn = bid % nbn;
  int tid = threadIdx.x;
  int lane = tid & 63;
  int wm = tid >> 7, wn = (tid >> 6) & 1;
  int g = lane >> 4, cl = lane & 15;
  f4 acc[4][4] = {};
  const _Float16* Ab = A + (size_t)bm*128*K;
  const _Float16* Bb = Bt + (size_t)bn*128*K;
  int s_row[4], s_off[4];
  #pragma unroll
  for (int i = 0; i < 4; ++i) {
    int s = tid + i*256;
    s_row[i] = s >> 3;
    s_off[i] = ((s & 7) ^ (s_row[i] & 7)) * 8;   // pre-swizzled global source (rule #21)
  }
  for (int kt = 0; kt < K; kt += 64) {
    #pragma unroll
    for (int i = 0; i < 4; ++i) {
      int s = tid + i*256;
      gload16(Ab + (size_t)s_row[i]*K + kt + s_off[i], (char*)Al + s*16);
      gload16(Bb + (size_t)s_row[i]*K + kt + s_off[i], (char*)Bl + s*16);
    }
    __syncthreads();
    #pragma unroll
    for (int kk = 0; kk < 2; ++kk) {
      h8 af[4], bf[4];
      #pragma unroll
      for (int mi = 0; mi < 4; ++mi) {
        int row = wm*64 + mi*16 + cl;
        int c = (kk*4 + g) ^ (row & 7);
        af[mi] = *(const h8*)((const char*)Al + row*128 + c*16);
      }
      #pragma unroll
      for (int ni = 0; ni < 4; ++ni) {
        int row = wn*64 + ni*16 + cl;
        int c = (kk*4 + g) ^ (row & 7);
        bf[ni] = *(const h8*)((const char*)Bl + row*128 + c*16);
      }
      #pragma unroll
      for (int mi = 0; mi < 4; ++mi)
        #pragma unroll
        for (int ni = 0; ni < 4; ++ni)
          acc[mi][ni] = __builtin_amdgcn_mfma_f32_16x16x32_f16(af[mi], bf[ni], acc[mi][ni], 0, 0, 0);
    }
    __syncthreads();
  }
  if (EPI == 1) {
    float bsv[4];
    #pragma unroll
    for (int ni = 0; ni < 4; ++ni) bsv[ni] = bias[bn*128 + wn*64 + ni*16 + cl];
    #pragma unroll
    for (int mi = 0; mi < 4; ++mi)
      #pragma unroll
      for (int r = 0; r < 4; ++r) {
        int m = bm*128 + wm*64 + mi*16 + g*4 + r;
        float* orow = Cf + (size_t)m*N + bn*128 + wn*64 + cl;
        #pragma unroll
        for (int ni = 0; ni < 4; ++ni)
          orow[ni*16] = acc[mi][ni][r] + bsv[ni];
      }
  } else {
    int region = (bn*128) >> 10;  // 0=Q 1=K 2=V (uniform per block: 128 | 1024)
    #pragma unroll
    for (int mi = 0; mi < 4; ++mi)
      #pragma unroll
      for (int r = 0; r < 4; ++r) {
        int m = bm*128 + wm*64 + mi*16 + g*4 + r;
        int b = m >> 11, l = m & 2047;
        #pragma unroll
        for (int ni = 0; ni < 4; ++ni) {
          int n = bn*128 + wn*64 + ni*16 + cl;
          int cc = n & 1023;
          int h = cc >> 6, d = cc & 63;
          _Float16 v = (_Float16)acc[mi][ni][r];
          if (region == 0)      Qo[(((size_t)b*16 + h)*2048 + l)*64 + d] = v;
          else if (region == 1) Ko[(((size_t)b*16 + h)*2048 + l)*64 + d] = v;
          else                  Vo[(((size_t)b*16 + h)*64 + d)*2048 + l] = v;
        }
      }
  }
}

// ---------------- causal flash attention ----------------
// 1 block per (head, 128-row q tile); 4 waves x 32 q-rows; KVBLK=64.
__global__ __launch_bounds__(256,2)
void k_attn(const _Float16* __restrict__ Q, const _Float16* __restrict__ K,
            const _Float16* __restrict__ Vt, _Float16* __restrict__ Oo) {
  __shared__ _Float16 Kl[64*64];       // [kv][d], xor-swizzled 16B chunks
  __shared__ _Float16 Vl[64*64];       // [d][kv], xor-swizzled
  __shared__ _Float16 Pl[4][32*64];    // per-wave P transpose buffer
  int bid = blockIdx.x;
  int bh = bid & 63;                   // bid%8==bh%8 -> head pinned to one XCD
  int qt = 15 - (bid >> 6);            // heavy tiles first
  int tid = threadIdx.x, lane = tid & 63, w = tid >> 6;
  int g = lane >> 4, cl = lane & 15;
  int qbase = qt*128;
  int qw = qbase + w*32;
  const _Float16* Qh = Q + (size_t)bh*L_*HD_;
  const _Float16* Kh = K + (size_t)bh*L_*HD_;
  const _Float16* Vh = Vt + (size_t)bh*HD_*L_;
  h8 qf[2][2];
  #pragma unroll
  for (int mi = 0; mi < 2; ++mi)
    #pragma unroll
    for (int kk = 0; kk < 2; ++kk)
      qf[mi][kk] = *(const h8*)(Qh + (size_t)(qw + mi*16 + cl)*64 + kk*32 + g*8);
  f4 oacc[2][4] = {};
  float mrun[2][4], lrun[2][4];
  #pragma unroll
  for (int mi = 0; mi < 2; ++mi)
    #pragma unroll
    for (int r = 0; r < 4; ++r) { mrun[mi][r] = -1e30f; lrun[mi][r] = 0.f; }
  const float csc = 0.125f * 1.4426950408889634f;   // scale * log2(e)
  int ntiles = (qbase >> 6) + 2;
  _Float16* Pw = &Pl[w][0];
  for (int t = 0; t < ntiles; ++t) {
    int kv0 = t*64;
    #pragma unroll
    for (int i = 0; i < 2; ++i) {
      int s = tid + i*256;
      int row = s >> 3;
      int c8 = ((s & 7) ^ (row & 7)) * 8;
      gload16(Kh + (size_t)(kv0 + row)*64 + c8, (char*)Kl + s*16);
      gload16(Vh + (size_t)row*L_ + kv0 + c8, (char*)Vl + s*16);
    }
    __syncthreads();
    if (kv0 <= qw + 31) {              // wave-level causal skip (barriers stay uniform)
      f4 sa[2][4] = {};
      #pragma unroll
      for (int kk = 0; kk < 2; ++kk) {
        h8 kf[4];
        #pragma unroll
        for (int ni = 0; ni < 4; ++ni) {
          int row = ni*16 + cl;
          int c = (kk*4 + g) ^ (row & 7);
          kf[ni] = *(const h8*)((const char*)Kl + row*128 + c*16);
        }
        #pragma unroll
        for (int mi = 0; mi < 2; ++mi)
          #pragma unroll
          for (int ni = 0; ni < 4; ++ni)
            sa[mi][ni] = __builtin_amdgcn_mfma_f32_16x16x32_f16(qf[mi][kk], kf[ni], sa[mi][ni], 0,0,0);
      }
      bool needm = (kv0 + 63) > qw;
      float tv[2][4][4];
      #pragma unroll
      for (int mi = 0; mi < 2; ++mi)
        #pragma unroll
        for (int ni = 0; ni < 4; ++ni)
          #pragma unroll
          for (int r = 0; r < 4; ++r) {
            float v = sa[mi][ni][r]*csc;
            if (needm) {
              int qi = qw + mi*16 + g*4 + r;
              int kv = kv0 + ni*16 + cl;
              if (kv > qi) v = -1e30f;
            }
            tv[mi][ni][r] = v;
          }
      #pragma unroll
      for (int mi = 0; mi < 2; ++mi)
        #pragma unroll
        for (int r = 0; r < 4; ++r) {
          float rm = fmaxf(fmaxf(tv[mi][0][r], tv[mi][1][r]), fmaxf(tv[mi][2][r], tv[mi][3][r]));
          rm = fmaxf(rm, __shfl_xor(rm, 1));
          rm = fmaxf(rm, __shfl_xor(rm, 2));
          rm = fmaxf(rm, __shfl_xor(rm, 4));
          rm = fmaxf(rm, __shfl_xor(rm, 8));
          float mold = mrun[mi][r];
          float mnew = fmaxf(mold, rm);
          float corr = exp2f(mold - mnew);
          mrun[mi][r] = mnew;
          float rs = 0.f;
          #pragma unroll
          for (int ni = 0; ni < 4; ++ni) {
            float p = exp2f(tv[mi][ni][r] - mnew);
            tv[mi][ni][r] = p;
            rs += p;
          }
          rs += __shfl_xor(rs, 1);
          rs += __shfl_xor(rs, 2);
          rs += __shfl_xor(rs, 4);
          rs += __shfl_xor(rs, 8);
          lrun[mi][r] = lrun[mi][r]*corr + rs;
          #pragma unroll
          for (int di = 0; di < 4; ++di) oacc[mi][di][r] *= corr;
        }
      // P (C-layout) -> wave-private LDS, swizzled; no barrier: wave-private, in-order DS
      #pragma unroll
      for (int mi = 0; mi < 2; ++mi)
        #pragma unroll
        for (int ni = 0; ni < 4; ++ni)
          #pragma unroll
          for (int r = 0; r < 4; ++r) {
            int row = mi*16 + g*4 + r;
            int col = ni*16 + cl;
            int c8 = (col >> 3) ^ (row & 7);
            *(_Float16*)((char*)Pw + row*128 + c8*16 + (col & 7)*2) = (_Float16)tv[mi][ni][r];
          }
      #pragma unroll
      for (int k2 = 0; k2 < 2; ++k2) {
        h8 pa[2], vf[4];
        #pragma unroll
        for (int mi = 0; mi < 2; ++mi) {
          int row = mi*16 + cl;
          int c = (k2*4 + g) ^ (row & 7);
          pa[mi] = *(const h8*)((const char*)Pw + row*128 + c*16);
        }
        #pragma unroll
        for (int di = 0; di < 4; ++di) {
          int row = di*16 + cl;
          int c = (k2*4 + g) ^ (row & 7);
          vf[di] = *(const h8*)((const char*)Vl + row*128 + c*16);
        }
        #pragma unroll
        for (int mi = 0; mi < 2; ++mi)
          #pragma unroll
          for (int di = 0; di < 4; ++di)
            oacc[mi][di] = __builtin_amdgcn_mfma_f32_16x16x32_f16(pa[mi], vf[di], oacc[mi][di], 0,0,0);
      }
    }
    __syncthreads();
  }
  int b = bh >> 4, h = bh & 15;
  #pragma unroll
  for (int mi = 0; mi < 2; ++mi)
    #pragma unroll
    for (int r = 0; r < 4; ++r) {
      float inv = 1.0f / lrun[mi][r];
      int qi = qw + mi*16 + g*4 + r;
      _Float16* orow = Oo + (((size_t)b*L_ + qi)*H_ + h)*HD_ + cl;
      #pragma unroll
      for (int di = 0; di < 4; ++di)
        orow[di*16] = (_Float16)(oacc[mi][di][r]*inv);
    }
}

// ---------------- launch ----------------
extern "C" void kernel_launch(void* const* d_in, const int* in_sizes, int n_in,
                              void* d_out, int out_size, void* d_ws, size_t ws_size,
                              hipStream_t stream) {
  const float* x      = (const float*)d_in[0];
  // d_in[1] = attn_mask: deterministic causal triu(k=1) -> reimplemented, not read
  const float* w_qkv  = (const float*)d_in[2];
  const float* w_proj = (const float*)d_in[3];
  const float* b_proj = (const float*)d_in[4];
  float* out = (float*)d_out;
  char* ws = (char*)d_ws;
  // layout (bytes): needs 72 MB total
  _Float16* xh     = (_Float16*)(ws);              // 16 MB, dead after gemm<0>
  _Float16* wqkvT  = (_Float16*)(ws + 16777216);   //  6 MB
  _Float16* wprojT = (_Float16*)(ws + 23068672);   //  2 MB
  _Float16* Qb     = (_Float16*)(ws + 25165824);   // 16 MB  (B,H,L,64)
  _Float16* Kb     = (_Float16*)(ws + 41943040);   // 16 MB  (B,H,L,64)
  _Float16* Vb     = (_Float16*)(ws + 58720256);   // 16 MB  (B,H,64,L) transposed
  _Float16* AOb    = xh;                           // alias: attn out (B,L,H,64)

  k_cvt_f16<<<2048, 256, 0, stream>>>(x, xh, (B_*L_*D_)/4);
  k_transpose_f16<<<dim3(N3_/32, D_/32), dim3(32,8), 0, stream>>>(w_qkv, wqkvT, D_, N3_);
  k_transpose_f16<<<dim3(D_/32, D_/32), dim3(32,8), 0, stream>>>(w_proj, wprojT, D_, D_);
  k_gemm<0><<<(M_/128)*(N3_/128), 256, 0, stream>>>(xh, wqkvT, nullptr, nullptr,
                                                    Qb, Kb, Vb, N3_, D_, N3_/128);
  k_attn<<<1024, 256, 0, stream>>>(Qb, Kb, Vb, AOb);
  k_gemm<1><<<(M_/128)*(D_/128), 256, 0, stream>>>(AOb, wprojT, out, b_proj,
                                                   nullptr, nullptr, nullptr, D_, D_, D_/128);
}

// Round 5
// 289.536 us; speedup vs baseline: 1.2540x; 1.2540x over previous
//
#include <hip/hip_runtime.h>
#include <stdint.h>

#define B_ 4
#define L_ 2048
#define D_ 1024
#define H_ 16
#define HD_ 64
#define M_ (B_*L_)   // 8192
#define N3_ (3*D_)   // 3072

typedef _Float16 h8 __attribute__((ext_vector_type(8)));
typedef _Float16 h4v __attribute__((ext_vector_type(4)));
typedef float f4 __attribute__((ext_vector_type(4)));

__device__ __forceinline__ void gload16(const void* g, void* l) {
  __builtin_amdgcn_global_load_lds(
      (const __attribute__((address_space(1))) void*)g,
      (__attribute__((address_space(3))) void*)l, 16, 0, 0);
}

// ---------------- conversion kernels ----------------
__global__ void k_cvt_f16(const float* __restrict__ in, _Float16* __restrict__ out, int n4) {
  int i = blockIdx.x*blockDim.x + threadIdx.x;
  int st = gridDim.x*blockDim.x;
  for (; i < n4; i += st) {
    float4 v = ((const float4*)in)[i];
    h4v o = { (_Float16)v.x, (_Float16)v.y, (_Float16)v.z, (_Float16)v.w };
    ((h4v*)out)[i] = o;
  }
}

// out[c][r] = (f16) in[r][c];  R,C multiples of 32
__global__ void k_transpose_f16(const float* __restrict__ in, _Float16* __restrict__ out, int R, int C) {
  __shared__ float tile[32][33];
  int bc = blockIdx.x*32, br = blockIdx.y*32;
  int tx = threadIdx.x, ty = threadIdx.y;
  #pragma unroll
  for (int j = 0; j < 32; j += 8)
    tile[ty+j][tx] = in[(size_t)(br+ty+j)*C + bc+tx];
  __syncthreads();
  #pragma unroll
  for (int j = 0; j < 32; j += 8)
    out[(size_t)(bc+ty+j)*R + br+tx] = (_Float16)tile[tx][ty+j];
}

// V (B,H,L,64) -> Vt (B,H,64,L); 64x64 tiles via swizzled LDS
__global__ __launch_bounds__(256,2)
void k_vtrans(const _Float16* __restrict__ Vi, _Float16* __restrict__ Vo) {
  __shared__ _Float16 T[64*64];
  int bh = blockIdx.x >> 5, lt = blockIdx.x & 31;
  int tid = threadIdx.x;
  const _Float16* src = Vi + ((size_t)bh*L_ + lt*64)*64;
  #pragma unroll
  for (int i = 0; i < 2; ++i) {
    int s = tid + i*256;
    int row = s >> 3;
    int swz = (row & 7) ^ ((row >> 3) & 7);
    int c8 = ((s & 7) ^ swz) * 8;
    gload16(src + row*64 + c8, (char*)T + s*16);
  }
  __syncthreads();
  #pragma unroll
  for (int i = 0; i < 2; ++i) {
    int s = tid + i*256;
    int d = s >> 3, c = s & 7;
    h8 v;
    #pragma unroll
    for (int k = 0; k < 8; ++k) {
      int l = c*8 + k;
      int swz = (l & 7) ^ ((l >> 3) & 7);
      int byteoff = (l*8 + ((d >> 3) ^ swz))*16 + (d & 7)*2;
      v[k] = *(const _Float16*)((const char*)T + byteoff);
    }
    *(h8*)(Vo + ((size_t)bh*64 + d)*L_ + lt*64 + c*8) = v;
  }
}

// ---------------- GEMM: C(MxN) = A(MxK) * Bt(NxK)^T ----------------
template<int EPI>
__global__ __launch_bounds__(256,2)
void k_gemm(const _Float16* __restrict__ A, const _Float16* __restrict__ Bt,
            float* __restrict__ Cf, const float* __restrict__ bias,
            _Float16* __restrict__ Qo, _Float16* __restrict__ Ko, _Float16* __restrict__ Vo,
            int N, int K, int nbn) {
  __shared__ _Float16 Al[128*64];
  __shared__ _Float16 Bl[128*64];
  int cpx = gridDim.x >> 3;                       // grid % 8 == 0 (bijective XCD swizzle)
  int bid = (blockIdx.x & 7)*cpx + (blockIdx.x >> 3);
  int bm = bid / nbn, bn = bid % nbn;
  int tid = threadIdx.x;
  int lane = tid & 63;
  int wm = tid >> 7, wn = (tid >> 6) & 1;
  int g = lane >> 4, cl = lane & 15;
  f4 acc[4][4] = {};
  const _Float16* Ab = A + (size_t)bm*128*K;
  const _Float16* Bb = Bt + (size_t)bn*128*K;
  int s_row[4], s_off[4];
  #pragma unroll
  for (int i = 0; i < 4; ++i) {
    int s = tid + i*256;
    s_row[i] = s >> 3;
    s_off[i] = ((s & 7) ^ (s_row[i] & 7)) * 8;
  }
  for (int kt = 0; kt < K; kt += 64) {
    #pragma unroll
    for (int i = 0; i < 4; ++i) {
      int s = tid + i*256;
      gload16(Ab + (size_t)s_row[i]*K + kt + s_off[i], (char*)Al + s*16);
      gload16(Bb + (size_t)s_row[i]*K + kt + s_off[i], (char*)Bl + s*16);
    }
    __syncthreads();
    #pragma unroll
    for (int kk = 0; kk < 2; ++kk) {
      h8 af[4], bf[4];
      #pragma unroll
      for (int mi = 0; mi < 4; ++mi) {
        int row = wm*64 + mi*16 + cl;
        int c = (kk*4 + g) ^ (row & 7);
        af[mi] = *(const h8*)((const char*)Al + row*128 + c*16);
      }
      #pragma unroll
      for (int ni = 0; ni < 4; ++ni) {
        int row = wn*64 + ni*16 + cl;
        int c = (kk*4 + g) ^ (row & 7);
        bf[ni] = *(const h8*)((const char*)Bl + row*128 + c*16);
      }
      #pragma unroll
      for (int mi = 0; mi < 4; ++mi)
        #pragma unroll
        for (int ni = 0; ni < 4; ++ni)
          acc[mi][ni] = __builtin_amdgcn_mfma_f32_16x16x32_f16(af[mi], bf[ni], acc[mi][ni], 0, 0, 0);
    }
    __syncthreads();
  }
  if (EPI == 1) {
    float bsv[4];
    #pragma unroll
    for (int ni = 0; ni < 4; ++ni) bsv[ni] = bias[bn*128 + wn*64 + ni*16 + cl];
    #pragma unroll
    for (int mi = 0; mi < 4; ++mi)
      #pragma unroll
      for (int r = 0; r < 4; ++r) {
        int m = bm*128 + wm*64 + mi*16 + g*4 + r;
        float* orow = Cf + (size_t)m*N + bn*128 + wn*64 + cl;
        #pragma unroll
        for (int ni = 0; ni < 4; ++ni)
          orow[ni*16] = acc[mi][ni][r] + bsv[ni];
      }
  } else {
    int region = (bn*128) >> 10;  // 0=Q 1=K 2=V (uniform per block)
    _Float16* P = (region == 0) ? Qo : (region == 1) ? Ko : Vo;
    float scl = (region == 0) ? 0.18033688011112042f : 1.0f;  // 1/sqrt(64)*log2(e) folded into Q
    #pragma unroll
    for (int mi = 0; mi < 4; ++mi)
      #pragma unroll
      for (int r = 0; r < 4; ++r) {
        int m = bm*128 + wm*64 + mi*16 + g*4 + r;
        int b = m >> 11, l = m & 2047;
        #pragma unroll
        for (int ni = 0; ni < 4; ++ni) {
          int n = bn*128 + wn*64 + ni*16 + cl;
          int cc = n & 1023;
          int h = cc >> 6, d = cc & 63;
          P[(((size_t)b*16 + h)*2048 + l)*64 + d] = (_Float16)(acc[mi][ni][r] * scl);
        }
      }
  }
}

// ---------------- causal flash attention (swapped QK^T, in-reg softmax) ----------------
__global__ __launch_bounds__(256,2)
void k_attn(const _Float16* __restrict__ Q, const _Float16* __restrict__ K,
            const _Float16* __restrict__ Vt, _Float16* __restrict__ Oo) {
  __shared__ _Float16 Kl[2][64*64];
  __shared__ _Float16 Vl[2][64*64];
  __shared__ _Float16 Pl[4][32*64];
  int bid = blockIdx.x;
  int bh = bid & 63;                   // bid%8==bh%8 -> head pinned to one XCD
  int qt = 15 - (bid >> 6);            // heavy tiles first
  int tid = threadIdx.x, lane = tid & 63, w = tid >> 6;
  int g = lane >> 4, cl = lane & 15;
  int qbase = qt*128;
  int qw = qbase + w*32;
  const _Float16* Qh = Q + (size_t)bh*L_*HD_;
  const _Float16* Kh = K + (size_t)bh*L_*HD_;
  const _Float16* Vh = Vt + (size_t)bh*HD_*L_;
  int srow[2], sc8[2];
  #pragma unroll
  for (int i = 0; i < 2; ++i) {
    int s = tid + i*256;
    srow[i] = s >> 3;
    sc8[i] = ((s & 7) ^ (srow[i] & 7)) * 8;
  }
  char* Pw = (char*)&Pl[w][0];
  int pq = cl*128;                     // per-lane P row base (q=cl); mi adds 2048
  h8 qf[2][2];
  #pragma unroll
  for (int mi = 0; mi < 2; ++mi)
    #pragma unroll
    for (int kk = 0; kk < 2; ++kk)
      qf[mi][kk] = *(const h8*)(Qh + (size_t)(qw + mi*16 + cl)*64 + kk*32 + g*8);
  f4 oacc[2][4] = {};
  float mrun[2] = {-1e30f, -1e30f}, lrun[2] = {0.f, 0.f};
  int ntiles = (qbase >> 6) + 2;

  auto stage = [&](int t, int buf) {
    int kv0s = t*64;
    #pragma unroll
    for (int i = 0; i < 2; ++i) {
      int s = tid + i*256;
      gload16(Kh + (size_t)(kv0s + srow[i])*64 + sc8[i], (char*)&Kl[buf][0] + s*16);
      gload16(Vh + (size_t)srow[i]*L_ + kv0s + sc8[i], (char*)&Vl[buf][0] + s*16);
    }
  };
  stage(0, 0);
  for (int t = 0; t < ntiles; ++t) {
    __syncthreads();                   // drains vmcnt(0): buf[t&1] ready
    if (t + 1 < ntiles) stage(t + 1, (t + 1) & 1);
    int kv0 = t*64;
    if (kv0 <= qw + 31) {
      const char* Kb = (const char*)&Kl[t & 1][0];
      const char* Vb = (const char*)&Vl[t & 1][0];
      f4 st[4][2] = {};                // [ni(kv)][mi(q)] -> S^T tiles
      __builtin_amdgcn_s_setprio(1);
      #pragma unroll
      for (int kk = 0; kk < 2; ++kk) {
        h8 kf[4];
        #pragma unroll
        for (int ni = 0; ni < 4; ++ni) {
          int row = ni*16 + cl;
          int c = (kk*4 + g) ^ (row & 7);
          kf[ni] = *(const h8*)(Kb + row*128 + c*16);
        }
        #pragma unroll
        for (int ni = 0; ni < 4; ++ni)
          #pragma unroll
          for (int mi = 0; mi < 2; ++mi)
            st[ni][mi] = __builtin_amdgcn_mfma_f32_16x16x32_f16(kf[ni], qf[mi][kk], st[ni][mi], 0,0,0);
      }
      __builtin_amdgcn_s_setprio(0);
      bool needm = (kv0 + 63) > qw;
      int srcb = (lane & 48) | ((lane >> 2) & 12);     // lane holding corr for q=g*4+r at r=0
      #pragma unroll
      for (int mi = 0; mi < 2; ++mi) {
        int qq = qw + mi*16 + cl;
        float p[4][4];
        #pragma unroll
        for (int ni = 0; ni < 4; ++ni)
          #pragma unroll
          for (int rr = 0; rr < 4; ++rr) {
            float v = st[ni][mi][rr];
            if (needm) {
              int kv = kv0 + ni*16 + g*4 + rr;
              if (kv > qq) v = -1e30f;
            }
            p[ni][rr] = v;
          }
        float rm = -1e30f;
        #pragma unroll
        for (int ni = 0; ni < 4; ++ni)
          rm = fmaxf(rm, fmaxf(fmaxf(p[ni][0], p[ni][1]), fmaxf(p[ni][2], p[ni][3])));
        rm = fmaxf(rm, __shfl_xor(rm, 16));
        rm = fmaxf(rm, __shfl_xor(rm, 32));
        float mold = mrun[mi];
        float mnew = fmaxf(mold, rm);
        float corr = exp2f(mold - mnew);
        mrun[mi] = mnew;
        float rs = 0.f;
        #pragma unroll
        for (int ni = 0; ni < 4; ++ni)
          #pragma unroll
          for (int rr = 0; rr < 4; ++rr) {
            float e = exp2f(p[ni][rr] - mnew);
            p[ni][rr] = e;
            rs += e;
          }
        rs += __shfl_xor(rs, 16);
        rs += __shfl_xor(rs, 32);
        lrun[mi] = lrun[mi]*corr + rs;
        float c0 = __shfl(corr, srcb);
        float c1 = __shfl(corr, srcb + 1);
        float c2 = __shfl(corr, srcb + 2);
        float c3 = __shfl(corr, srcb + 3);
        #pragma unroll
        for (int di = 0; di < 4; ++di) {
          oacc[mi][di][0] *= c0; oacc[mi][di][1] *= c1;
          oacc[mi][di][2] *= c2; oacc[mi][di][3] *= c3;
        }
        // pack P quads (kv+0..3) -> swizzled wave-private LDS (b64 writes)
        #pragma unroll
        for (int ni = 0; ni < 4; ++ni) {
          auto lo = __builtin_amdgcn_cvt_pkrtz(p[ni][0], p[ni][1]);
          auto hi = __builtin_amdgcn_cvt_pkrtz(p[ni][2], p[ni][3]);
          uint2 q4;
          q4.x = __builtin_bit_cast(unsigned int, lo);
          q4.y = __builtin_bit_cast(unsigned int, hi);
          int off = pq + mi*2048 + (((ni*2 + (g >> 1)) ^ (cl & 7)) << 4) + (g & 1)*8;
          *(uint2*)(Pw + off) = q4;
        }
      }
      __builtin_amdgcn_s_setprio(1);
      #pragma unroll
      for (int ks = 0; ks < 2; ++ks) {
        h8 pa[2], vf[4];
        #pragma unroll
        for (int mi = 0; mi < 2; ++mi)
          pa[mi] = *(const h8*)(Pw + pq + mi*2048 + (((ks*4 + g) ^ (cl & 7)) << 4));
        #pragma unroll
        for (int di = 0; di < 4; ++di) {
          int row = di*16 + cl;
          int c = (ks*4 + g) ^ (row & 7);
          vf[di] = *(const h8*)(Vb + row*128 + c*16);
        }
        #pragma unroll
        for (int mi = 0; mi < 2; ++mi)
          #pragma unroll
          for (int di = 0; di < 4; ++di)
            oacc[mi][di] = __builtin_amdgcn_mfma_f32_16x16x32_f16(pa[mi], vf[di], oacc[mi][di], 0,0,0);
      }
      __builtin_amdgcn_s_setprio(0);
    }
  }
  int b = bh >> 4, h = bh & 15;
  int srcb = (lane & 48) | ((lane >> 2) & 12);
  #pragma unroll
  for (int mi = 0; mi < 2; ++mi) {
    float inv = 1.0f / lrun[mi];
    float iv[4];
    iv[0] = __shfl(inv, srcb);
    iv[1] = __shfl(inv, srcb + 1);
    iv[2] = __shfl(inv, srcb + 2);
    iv[3] = __shfl(inv, srcb + 3);
    #pragma unroll
    for (int r = 0; r < 4; ++r) {
      int qi = qw + mi*16 + g*4 + r;
      _Float16* orow = Oo + (((size_t)b*L_ + qi)*H_ + h)*HD_ + cl;
      #pragma unroll
      for (int di = 0; di < 4; ++di)
        orow[di*16] = (_Float16)(oacc[mi][di][r] * iv[r]);
    }
  }
}

// ---------------- launch ----------------
extern "C" void kernel_launch(void* const* d_in, const int* in_sizes, int n_in,
                              void* d_out, int out_size, void* d_ws, size_t ws_size,
                              hipStream_t stream) {
  const float* x      = (const float*)d_in[0];
  // d_in[1] = attn_mask: deterministic causal triu(k=1) -> reimplemented, not read
  const float* w_qkv  = (const float*)d_in[2];
  const float* w_proj = (const float*)d_in[3];
  const float* b_proj = (const float*)d_in[4];
  float* out = (float*)d_out;
  char* ws = (char*)d_ws;
  // layout (72 MB):
  _Float16* xh     = (_Float16*)(ws);              // 16 MB (gemm<0> A); dead after -> Vtb
  _Float16* wqkvT  = (_Float16*)(ws + 16777216);   //  6 MB
  _Float16* wprojT = (_Float16*)(ws + 23068672);   //  2 MB
  _Float16* Qb     = (_Float16*)(ws + 25165824);   // 16 MB (B,H,L,64), pre-scaled
  _Float16* Kb     = (_Float16*)(ws + 41943040);   // 16 MB (B,H,L,64)
  _Float16* Vtmp   = (_Float16*)(ws + 58720256);   // 16 MB (B,H,L,64); dead after vtrans -> AOb
  _Float16* Vtb    = xh;                           // (B,H,64,L)
  _Float16* AOb    = Vtmp;                         // attn out (B,L,H,64)

  k_cvt_f16<<<2048, 256, 0, stream>>>(x, xh, (B_*L_*D_)/4);
  k_transpose_f16<<<dim3(N3_/32, D_/32), dim3(32,8), 0, stream>>>(w_qkv, wqkvT, D_, N3_);
  k_transpose_f16<<<dim3(D_/32, D_/32), dim3(32,8), 0, stream>>>(w_proj, wprojT, D_, D_);
  k_gemm<0><<<(M_/128)*(N3_/128), 256, 0, stream>>>(xh, wqkvT, nullptr, nullptr,
                                                    Qb, Kb, Vtmp, N3_, D_, N3_/128);
  k_vtrans<<<2048, 256, 0, stream>>>(Vtmp, Vtb);
  k_attn<<<1024, 256, 0, stream>>>(Qb, Kb, Vtb, AOb);
  k_gemm<1><<<(M_/128)*(D_/128), 256, 0, stream>>>(AOb, wprojT, out, b_proj,
                                                   nullptr, nullptr, nullptr, D_, D_, D_/128);
}

// Round 6
// 274.410 us; speedup vs baseline: 1.3231x; 1.0551x over previous
//
#include <hip/hip_runtime.h>
#include <stdint.h>

#define B_ 4
#define L_ 2048
#define D_ 1024
#define H_ 16
#define HD_ 64
#define M_ (B_*L_)   // 8192
#define N3_ (3*D_)   // 3072

typedef _Float16 h8 __attribute__((ext_vector_type(8)));
typedef _Float16 h4v __attribute__((ext_vector_type(4)));
typedef float f4 __attribute__((ext_vector_type(4)));
typedef float f16v __attribute__((ext_vector_type(16)));
typedef unsigned int u32x4 __attribute__((ext_vector_type(4)));

__device__ __forceinline__ void gload16(const void* g, void* l) {
  __builtin_amdgcn_global_load_lds(
      (const __attribute__((address_space(1))) void*)g,
      (__attribute__((address_space(3))) void*)l, 16, 0, 0);
}

// ---------------- conversion kernels ----------------
__global__ void k_cvt_f16(const float* __restrict__ in, _Float16* __restrict__ out, int n4) {
  int i = blockIdx.x*blockDim.x + threadIdx.x;
  int st = gridDim.x*blockDim.x;
  for (; i < n4; i += st) {
    float4 v = ((const float4*)in)[i];
    h4v o = { (_Float16)v.x, (_Float16)v.y, (_Float16)v.z, (_Float16)v.w };
    ((h4v*)out)[i] = o;
  }
}

// out[c][r] = (f16) in[r][c];  R,C multiples of 32
__global__ void k_transpose_f16(const float* __restrict__ in, _Float16* __restrict__ out, int R, int C) {
  __shared__ float tile[32][33];
  int bc = blockIdx.x*32, br = blockIdx.y*32;
  int tx = threadIdx.x, ty = threadIdx.y;
  #pragma unroll
  for (int j = 0; j < 32; j += 8)
    tile[ty+j][tx] = in[(size_t)(br+ty+j)*C + bc+tx];
  __syncthreads();
  #pragma unroll
  for (int j = 0; j < 32; j += 8)
    out[(size_t)(bc+ty+j)*R + br+tx] = (_Float16)tile[tx][ty+j];
}

// V (B,H,L,64) -> Vt (B,H,64,L); 64x64 tiles via swizzled LDS
__global__ __launch_bounds__(256,2)
void k_vtrans(const _Float16* __restrict__ Vi, _Float16* __restrict__ Vo) {
  __shared__ _Float16 T[64*64];
  int bh = blockIdx.x >> 5, lt = blockIdx.x & 31;
  int tid = threadIdx.x;
  const _Float16* src = Vi + ((size_t)bh*L_ + lt*64)*64;
  #pragma unroll
  for (int i = 0; i < 2; ++i) {
    int s = tid + i*256;
    int row = s >> 3;
    int swz = (row & 7) ^ ((row >> 3) & 7);
    int c8 = ((s & 7) ^ swz) * 8;
    gload16(src + row*64 + c8, (char*)T + s*16);
  }
  __syncthreads();
  #pragma unroll
  for (int i = 0; i < 2; ++i) {
    int s = tid + i*256;
    int d = s >> 3, c = s & 7;
    h8 v;
    #pragma unroll
    for (int k = 0; k < 8; ++k) {
      int l = c*8 + k;
      int swz = (l & 7) ^ ((l >> 3) & 7);
      int byteoff = (l*8 + ((d >> 3) ^ swz))*16 + (d & 7)*2;
      v[k] = *(const _Float16*)((const char*)T + byteoff);
    }
    *(h8*)(Vo + ((size_t)bh*64 + d)*L_ + lt*64 + c*8) = v;
  }
}

// ---------------- GEMM: C(MxN) = A(MxK) * Bt(NxK)^T ----------------
template<int EPI>
__global__ __launch_bounds__(256,2)
void k_gemm(const _Float16* __restrict__ A, const _Float16* __restrict__ Bt,
            float* __restrict__ Cf, const float* __restrict__ bias,
            _Float16* __restrict__ Qo, _Float16* __restrict__ Ko, _Float16* __restrict__ Vo,
            int N, int K, int nbn) {
  __shared__ _Float16 Al[128*64];
  __shared__ _Float16 Bl[128*64];
  int cpx = gridDim.x >> 3;                       // grid % 8 == 0 (bijective XCD swizzle)
  int bid = (blockIdx.x & 7)*cpx + (blockIdx.x >> 3);
  int bm = bid / nbn, bn = bid % nbn;
  int tid = threadIdx.x;
  int lane = tid & 63;
  int wm = tid >> 7, wn = (tid >> 6) & 1;
  int g = lane >> 4, cl = lane & 15;
  f4 acc[4][4] = {};
  const _Float16* Ab = A + (size_t)bm*128*K;
  const _Float16* Bb = Bt + (size_t)bn*128*K;
  int s_row[4], s_off[4];
  #pragma unroll
  for (int i = 0; i < 4; ++i) {
    int s = tid + i*256;
    s_row[i] = s >> 3;
    s_off[i] = ((s & 7) ^ (s_row[i] & 7)) * 8;
  }
  for (int kt = 0; kt < K; kt += 64) {
    #pragma unroll
    for (int i = 0; i < 4; ++i) {
      int s = tid + i*256;
      gload16(Ab + (size_t)s_row[i]*K + kt + s_off[i], (char*)Al + s*16);
      gload16(Bb + (size_t)s_row[i]*K + kt + s_off[i], (char*)Bl + s*16);
    }
    __syncthreads();
    #pragma unroll
    for (int kk = 0; kk < 2; ++kk) {
      h8 af[4], bf[4];
      #pragma unroll
      for (int mi = 0; mi < 4; ++mi) {
        int row = wm*64 + mi*16 + cl;
        int c = (kk*4 + g) ^ (row & 7);
        af[mi] = *(const h8*)((const char*)Al + row*128 + c*16);
      }
      #pragma unroll
      for (int ni = 0; ni < 4; ++ni) {
        int row = wn*64 + ni*16 + cl;
        int c = (kk*4 + g) ^ (row & 7);
        bf[ni] = *(const h8*)((const char*)Bl + row*128 + c*16);
      }
      #pragma unroll
      for (int mi = 0; mi < 4; ++mi)
        #pragma unroll
        for (int ni = 0; ni < 4; ++ni)
          acc[mi][ni] = __builtin_amdgcn_mfma_f32_16x16x32_f16(af[mi], bf[ni], acc[mi][ni], 0, 0, 0);
    }
    __syncthreads();
  }
  if (EPI == 1) {
    float bsv[4];
    #pragma unroll
    for (int ni = 0; ni < 4; ++ni) bsv[ni] = bias[bn*128 + wn*64 + ni*16 + cl];
    #pragma unroll
    for (int mi = 0; mi < 4; ++mi)
      #pragma unroll
      for (int r = 0; r < 4; ++r) {
        int m = bm*128 + wm*64 + mi*16 + g*4 + r;
        float* orow = Cf + (size_t)m*N + bn*128 + wn*64 + cl;
        #pragma unroll
        for (int ni = 0; ni < 4; ++ni)
          orow[ni*16] = acc[mi][ni][r] + bsv[ni];
      }
  } else {
    int region = (bn*128) >> 10;  // 0=Q 1=K 2=V (uniform per block)
    _Float16* P = (region == 0) ? Qo : (region == 1) ? Ko : Vo;
    float scl = (region == 0) ? 0.18033688011112042f : 1.0f;  // 1/sqrt(64)*log2(e) folded into Q
    #pragma unroll
    for (int mi = 0; mi < 4; ++mi)
      #pragma unroll
      for (int r = 0; r < 4; ++r) {
        int m = bm*128 + wm*64 + mi*16 + g*4 + r;
        int b = m >> 11, l = m & 2047;
        #pragma unroll
        for (int ni = 0; ni < 4; ++ni) {
          int n = bn*128 + wn*64 + ni*16 + cl;
          int cc = n & 1023;
          int h = cc >> 6, d = cc & 63;
          P[(((size_t)b*16 + h)*2048 + l)*64 + d] = (_Float16)(acc[mi][ni][r] * scl);
        }
      }
  }
}

// ---------------- causal flash attention (32x32 MFMA, lane-local softmax) ----------------
// S^T = mfma32(K,Q): col=q=lane&31 -> one q per lane pair; P stays in registers,
// PV = mfma32(Vt, P) accumulates O^T[d][q] with the same col=q layout.
__global__ __launch_bounds__(256,2)
void k_attn(const _Float16* __restrict__ Q, const _Float16* __restrict__ K,
            const _Float16* __restrict__ Vt, _Float16* __restrict__ Oo) {
  __shared__ _Float16 Kl[2][64*64];    // [kv][d] rows 128B, xor-swizzled 16B chunks
  __shared__ _Float16 Vl[2][64*64];    // [d][kv] rows 128B, xor-swizzled
  int bid = blockIdx.x;
  int bh = bid & 63;                   // bid%8==bh%8 -> head pinned to one XCD
  int qt = 15 - (bid >> 6);            // heavy tiles first
  int tid = threadIdx.x, lane = tid & 63, w = tid >> 6;
  int l31 = lane & 31, hf = lane >> 5;
  int qbase = qt*128;
  int qw = qbase + w*32;
  int q = qw + l31;                    // this lane's q-row (shared with lane^32)
  const _Float16* Qh = Q + (size_t)bh*L_*HD_;
  const _Float16* Kh = K + (size_t)bh*L_*HD_;
  const _Float16* Vh = Vt + (size_t)bh*HD_*L_;
  int srow[2], sc8[2];
  #pragma unroll
  for (int i = 0; i < 2; ++i) {
    int s = tid + i*256;
    srow[i] = s >> 3;
    sc8[i] = ((s & 7) ^ (srow[i] & 7)) * 8;
  }
  // Q B-frag: lane holds Q[q][kd*16 + hf*8 .. +7] for kd=0..3 (pre-scaled by 1/8*log2e)
  h8 qf[4];
  #pragma unroll
  for (int kd = 0; kd < 4; ++kd)
    qf[kd] = *(const h8*)(Qh + (size_t)q*64 + kd*16 + hf*8);
  f16v oacc[2] = {};                   // O^T[d][q], d-blocks 0-31 / 32-63
  float mrun = -1e30f, lrun = 0.f;
  int ntiles = (qbase >> 6) + 2;

  auto stage = [&](int t, int buf) {
    int kv0s = t*64;
    #pragma unroll
    for (int i = 0; i < 2; ++i) {
      int s = tid + i*256;
      gload16(Kh + (size_t)(kv0s + srow[i])*64 + sc8[i], (char*)&Kl[buf][0] + s*16);
      gload16(Vh + (size_t)srow[i]*L_ + kv0s + sc8[i], (char*)&Vl[buf][0] + s*16);
    }
  };
  stage(0, 0);
  for (int t = 0; t < ntiles; ++t) {
    __syncthreads();                   // drains vmcnt(0): buf[t&1] ready
    if (t + 1 < ntiles) stage(t + 1, (t + 1) & 1);
    int kv0 = t*64;
    if (kv0 <= qw + 31) {              // wave-level causal skip (barriers stay uniform)
      const char* Kb = (const char*)&Kl[t & 1][0];
      const char* Vb = (const char*)&Vl[t & 1][0];
      // ---- QK^T: S^T[kv][q] ----
      f16v st[2] = {};
      __builtin_amdgcn_s_setprio(1);
      #pragma unroll
      for (int kb = 0; kb < 2; ++kb)
        #pragma unroll
        for (int kd = 0; kd < 4; ++kd) {
          int r = kb*32 + l31;
          int c = (kd*2 + hf) ^ (r & 7);
          h8 kf = *(const h8*)(Kb + r*128 + c*16);
          st[kb] = __builtin_amdgcn_mfma_f32_32x32x16_f16(kf, qf[kd], st[kb], 0, 0, 0);
        }
      __builtin_amdgcn_s_setprio(0);
      // ---- mask + softmax (per-lane scalar state) ----
      bool needm = (kv0 + 63) > qw;
      float p[2][16];
      #pragma unroll
      for (int kb = 0; kb < 2; ++kb)
        #pragma unroll
        for (int rg = 0; rg < 16; ++rg) {
          float v = st[kb][rg];
          if (needm) {
            int kv = kv0 + kb*32 + (rg & 3) + 8*(rg >> 2) + 4*hf;
            if (kv > q) v = -1e30f;
          }
          p[kb][rg] = v;
        }
      float rm = -1e30f;
      #pragma unroll
      for (int kb = 0; kb < 2; ++kb)
        #pragma unroll
        for (int rg = 0; rg < 16; ++rg) rm = fmaxf(rm, p[kb][rg]);
      rm = fmaxf(rm, __shfl_xor(rm, 32));
      if (!__all(rm <= mrun + 8.f)) {  // defer-max (T13): skip rescale when max barely grows
        float mnew = fmaxf(mrun, rm);
        float corr = exp2f(mrun - mnew);
        mrun = mnew;
        lrun *= corr;
        #pragma unroll
        for (int db = 0; db < 2; ++db)
          #pragma unroll
          for (int rg = 0; rg < 16; ++rg) oacc[db][rg] *= corr;
      }
      float rs = 0.f;
      #pragma unroll
      for (int kb = 0; kb < 2; ++kb)
        #pragma unroll
        for (int rg = 0; rg < 16; ++rg) {
          float e = exp2f(p[kb][rg] - mrun);
          p[kb][rg] = e;
          rs += e;
        }
      rs += __shfl_xor(rs, 32);
      lrun += rs;
      // ---- pack P -> B-frag (kv 16-blocks), half-exchange across lane^32 ----
      h8 pb[4];
      #pragma unroll
      for (int blk = 0; blk < 4; ++blk) {
        int kb = blk >> 1, sb = (blk & 1)*8;
        unsigned dw0 = __builtin_bit_cast(unsigned, __builtin_amdgcn_cvt_pkrtz(p[kb][sb+0], p[kb][sb+1]));
        unsigned dw1 = __builtin_bit_cast(unsigned, __builtin_amdgcn_cvt_pkrtz(p[kb][sb+2], p[kb][sb+3]));
        unsigned dw2 = __builtin_bit_cast(unsigned, __builtin_amdgcn_cvt_pkrtz(p[kb][sb+4], p[kb][sb+5]));
        unsigned dw3 = __builtin_bit_cast(unsigned, __builtin_amdgcn_cvt_pkrtz(p[kb][sb+6], p[kb][sb+7]));
        unsigned eu = hf ? dw0 : dw2;
        unsigned ev = hf ? dw1 : dw3;
        unsigned up = (unsigned)__shfl_xor((int)eu, 32);
        unsigned vp = (unsigned)__shfl_xor((int)ev, 32);
        u32x4 tmp;
        if (hf == 0) tmp = (u32x4){dw0, dw1, up, vp};
        else         tmp = (u32x4){up, vp, dw2, dw3};
        pb[blk] = __builtin_bit_cast(h8, tmp);
      }
      // ---- PV: O^T[d][q] += V^T x P ----
      __builtin_amdgcn_s_setprio(1);
      #pragma unroll
      for (int db = 0; db < 2; ++db)
        #pragma unroll
        for (int ks = 0; ks < 4; ++ks) {
          int r = db*32 + l31;
          int c = (ks*2 + hf) ^ (r & 7);
          h8 vf = *(const h8*)(Vb + r*128 + c*16);
          oacc[db] = __builtin_amdgcn_mfma_f32_32x32x16_f16(vf, pb[ks], oacc[db], 0, 0, 0);
        }
      __builtin_amdgcn_s_setprio(0);
    }
  }
  // ---- epilogue: O[q][d] = oacc^T / lrun, packed 8B stores ----
  float inv = 1.0f / lrun;
  int b = bh >> 4, hh = bh & 15;
  _Float16* obase = Oo + (((size_t)b*L_ + q)*H_ + hh)*HD_;
  #pragma unroll
  for (int db = 0; db < 2; ++db)
    #pragma unroll
    for (int grp = 0; grp < 4; ++grp) {
      unsigned lo = __builtin_bit_cast(unsigned,
          __builtin_amdgcn_cvt_pkrtz(oacc[db][grp*4+0]*inv, oacc[db][grp*4+1]*inv));
      unsigned hi = __builtin_bit_cast(unsigned,
          __builtin_amdgcn_cvt_pkrtz(oacc[db][grp*4+2]*inv, oacc[db][grp*4+3]*inv));
      uint2 qq; qq.x = lo; qq.y = hi;
      *(uint2*)(obase + db*32 + grp*8 + 4*hf) = qq;
    }
}

// ---------------- launch ----------------
extern "C" void kernel_launch(void* const* d_in, const int* in_sizes, int n_in,
                              void* d_out, int out_size, void* d_ws, size_t ws_size,
                              hipStream_t stream) {
  const float* x      = (const float*)d_in[0];
  // d_in[1] = attn_mask: deterministic causal triu(k=1) -> reimplemented, not read
  const float* w_qkv  = (const float*)d_in[2];
  const float* w_proj = (const float*)d_in[3];
  const float* b_proj = (const float*)d_in[4];
  float* out = (float*)d_out;
  char* ws = (char*)d_ws;
  // layout (72 MB):
  _Float16* xh     = (_Float16*)(ws);              // 16 MB (gemm<0> A); dead after -> Vtb
  _Float16* wqkvT  = (_Float16*)(ws + 16777216);   //  6 MB
  _Float16* wprojT = (_Float16*)(ws + 23068672);   //  2 MB
  _Float16* Qb     = (_Float16*)(ws + 25165824);   // 16 MB (B,H,L,64), pre-scaled
  _Float16* Kb     = (_Float16*)(ws + 41943040);   // 16 MB (B,H,L,64)
  _Float16* Vtmp   = (_Float16*)(ws + 58720256);   // 16 MB (B,H,L,64); dead after vtrans -> AOb
  _Float16* Vtb    = xh;                           // (B,H,64,L)
  _Float16* AOb    = Vtmp;                         // attn out (B,L,H,64)

  k_cvt_f16<<<2048, 256, 0, stream>>>(x, xh, (B_*L_*D_)/4);
  k_transpose_f16<<<dim3(N3_/32, D_/32), dim3(32,8), 0, stream>>>(w_qkv, wqkvT, D_, N3_);
  k_transpose_f16<<<dim3(D_/32, D_/32), dim3(32,8), 0, stream>>>(w_proj, wprojT, D_, D_);
  k_gemm<0><<<(M_/128)*(N3_/128), 256, 0, stream>>>(xh, wqkvT, nullptr, nullptr,
                                                    Qb, Kb, Vtmp, N3_, D_, N3_/128);
  k_vtrans<<<2048, 256, 0, stream>>>(Vtmp, Vtb);
  k_attn<<<1024, 256, 0, stream>>>(Qb, Kb, Vtb, AOb);
  k_gemm<1><<<(M_/128)*(D_/128), 256, 0, stream>>>(AOb, wprojT, out, b_proj,
                                                   nullptr, nullptr, nullptr, D_, D_, D_/128);
}